// Round 1
// 8122.541 us; speedup vs baseline: 4.6080x; 4.6080x over previous
//
#include <hip/hip_runtime.h>
#include <hip/hip_bf16.h>
#include <math.h>

#define NLAYERS 6
#define NHEADS  8
#define HDIM    64
#define DMODEL  512
#define FDIM    2048
#define BSZ     8
#define LSRC    512
#define LTGT    256
#define VOCAB   32000

// ---------- embedding + (buggy) positional encoding ----------
// pe[b, 2i] = sin(b * 10000^(-2i/D)), pe[b, 2i+1] = cos(same) — depends on the
// batch index only (faithful to the reference's pe[:x.size(0)] slice bug).
__global__ __launch_bounds__(256) void embed_pe_kernel(
    const int* __restrict__ tok, const float* __restrict__ emb,
    float* __restrict__ out, int S)
{
    int i = blockIdx.x * 256 + threadIdx.x;   // over B*S*512
    int d  = i & 511;
    int bs = i >> 9;
    int b  = bs / S;
    int t  = tok[bs];
    float e   = emb[(size_t)t * DMODEL + d];
    float dv  = expf(-(float)(d & ~1) * 0.017988946039016f);  // ln(10000)/512
    float ang = (float)b * dv;
    float pe  = (d & 1) ? cosf(ang) : sinf(ang);
    out[i] = e + pe;
}

// ---------- layernorm (row = 512) ----------
__global__ __launch_bounds__(256) void layernorm_kernel(
    const float* __restrict__ x, const float* __restrict__ g,
    const float* __restrict__ b, float* __restrict__ out)
{
    int row = blockIdx.x;
    int tid = threadIdx.x;
    const float* xr = x + (size_t)row * DMODEL;
    float v0 = xr[tid], v1 = xr[tid + 256];
    __shared__ float red[256];
    red[tid] = v0 + v1;
    __syncthreads();
    for (int s = 128; s; s >>= 1) { if (tid < s) red[tid] += red[tid + s]; __syncthreads(); }
    float mean = red[0] * (1.0f / 512.0f);
    __syncthreads();
    float d0 = v0 - mean, d1 = v1 - mean;
    red[tid] = d0 * d0 + d1 * d1;
    __syncthreads();
    for (int s = 128; s; s >>= 1) { if (tid < s) red[tid] += red[tid + s]; __syncthreads(); }
    float rstd = rsqrtf(red[0] * (1.0f / 512.0f) + 1e-6f);
    float* orow = out + (size_t)row * DMODEL;
    orow[tid]       = d0 * rstd * g[tid]       + b[tid];
    orow[tid + 256] = d1 * rstd * g[tid + 256] + b[tid + 256];
}

// ---------- fp32 tiled GEMM: C[M,N] = A[M,K] @ B[K,N] + bias
//            (+ residual) (ReLU optional). M%64==0, N%64==0, K%16==0.
// LDS stride 68 (= 4 mod 32 banks): fragment reads are aligned ds_read_b128,
// 2-way/broadcast bank pattern (free per m136).
__global__ __launch_bounds__(256) void gemm_kernel(
    const float* __restrict__ A, const float* __restrict__ B,
    const float* __restrict__ bias, const float* __restrict__ residual,
    float* __restrict__ C, int M, int N, int K, int relu)
{
    __shared__ float As[16][68];   // [k][row]
    __shared__ float Bs[16][68];   // [k][col]
    int tid = threadIdx.x;
    int tx = tid & 15;             // 4 output cols each
    int ty = tid >> 4;             // 4 output rows each
    int brow = blockIdx.y * 64;
    int bcol = blockIdx.x * 64;
    float acc[4][4] = {};
    for (int k0 = 0; k0 < K; k0 += 16) {
        #pragma unroll
        for (int i = 0; i < 4; i++) {
            int idx = tid + i * 256;     // 0..1023
            int r = idx >> 4, c = idx & 15;
            As[c][r] = A[(size_t)(brow + r) * K + k0 + c];
        }
        #pragma unroll
        for (int i = 0; i < 4; i++) {
            int idx = tid + i * 256;
            int r = idx >> 6, c = idx & 63;
            Bs[r][c] = B[(size_t)(k0 + r) * N + bcol + c];
        }
        __syncthreads();
        #pragma unroll
        for (int kk = 0; kk < 16; kk++) {
            float4 a4 = *(const float4*)&As[kk][ty * 4];
            float4 b4 = *(const float4*)&Bs[kk][tx * 4];
            float a[4] = {a4.x, a4.y, a4.z, a4.w};
            float b[4] = {b4.x, b4.y, b4.z, b4.w};
            #pragma unroll
            for (int i = 0; i < 4; i++)
                #pragma unroll
                for (int j = 0; j < 4; j++) acc[i][j] += a[i] * b[j];
        }
        __syncthreads();
    }
    float4 bias4 = *(const float4*)&bias[bcol + tx * 4];
    float bb[4] = {bias4.x, bias4.y, bias4.z, bias4.w};
    #pragma unroll
    for (int i = 0; i < 4; i++) {
        int row = brow + ty * 4 + i;
        float v[4];
        #pragma unroll
        for (int j = 0; j < 4; j++) v[j] = acc[i][j] + bb[j];
        if (residual) {
            float4 r4 = *(const float4*)&residual[(size_t)row * N + bcol + tx * 4];
            v[0] += r4.x; v[1] += r4.y; v[2] += r4.z; v[3] += r4.w;
        }
        if (relu) {
            #pragma unroll
            for (int j = 0; j < 4; j++) v[j] = fmaxf(v[j], 0.0f);
        }
        *(float4*)&C[(size_t)row * N + bcol + tx * 4] = make_float4(v[0], v[1], v[2], v[3]);
    }
}

// ---------- flash-style attention: one block per (b, h, 64-query tile) ----------
// Q:[B,SQ,512] K,V:[B,SK,512] row-major; head h occupies cols [h*64, h*64+64).
// mask_mode 0: mask[B*SK] (broadcast over q); 1: mask[B*SQ*SK]
// Per k-tile of 64: stage K^T and V in LDS, 4x4 register-tile score GEMM,
// online softmax (shfl_xor across the 16 tx lanes that share a q-row),
// write P^T into the K buffer, PV GEMM from LDS. Mask semantics identical to
// reference (-1e9 fill), including the fully-masked-row -> uniform case.
__global__ __launch_bounds__(256) void attn_kernel(
    const float* __restrict__ Q, const float* __restrict__ K,
    const float* __restrict__ V, const int* __restrict__ mask,
    int mask_mode, float* __restrict__ out, int SQ, int SK)
{
    const int HD = NHEADS * HDIM;   // 512
    int tid = threadIdx.x;
    int tx = tid & 15;              // 4 score-cols / output d-cols each
    int ty = tid >> 4;              // 4 q-rows each
    int q0 = blockIdx.x * 64;
    int h = blockIdx.y, b = blockIdx.z;

    __shared__ float Qs[64][68];    // [d][q]
    __shared__ float KPs[64][68];   // [d][k] while scoring; [k][q] as P after
    __shared__ float Vs[64][68];    // [k][d]

    // stage Q tile transposed: Qs[d][q] = Q[b, q0+q, h*64+d]
    const float4* Qp4 = (const float4*)(Q + ((size_t)b * SQ + q0) * HD + h * HDIM);
    #pragma unroll
    for (int i = 0; i < 4; i++) {
        int f = tid + i * 256;              // float4 index over 64x16
        int q = f >> 4, c = f & 15;
        float4 qv = Qp4[q * (HD / 4) + c];
        int d = c * 4;
        Qs[d + 0][q] = qv.x; Qs[d + 1][q] = qv.y;
        Qs[d + 2][q] = qv.z; Qs[d + 3][q] = qv.w;
    }

    float m[4], l[4], o[4][4];
    #pragma unroll
    for (int i = 0; i < 4; i++) {
        m[i] = -INFINITY; l[i] = 0.0f;
        #pragma unroll
        for (int j = 0; j < 4; j++) o[i][j] = 0.0f;
    }

    for (int k0 = 0; k0 < SK; k0 += 64) {
        __syncthreads();   // Qs visible (iter 0); KPs/Vs free from prev iter
        const float4* Kp4 = (const float4*)(K + ((size_t)b * SK + k0) * HD + h * HDIM);
        const float4* Vp4 = (const float4*)(V + ((size_t)b * SK + k0) * HD + h * HDIM);
        #pragma unroll
        for (int i = 0; i < 4; i++) {
            int f = tid + i * 256;
            int k = f >> 4, c = f & 15;
            float4 kv = Kp4[k * (HD / 4) + c];
            float4 vv = Vp4[k * (HD / 4) + c];
            int d = c * 4;
            KPs[d + 0][k] = kv.x; KPs[d + 1][k] = kv.y;
            KPs[d + 2][k] = kv.z; KPs[d + 3][k] = kv.w;
            *(float4*)&Vs[k][d] = vv;
        }
        __syncthreads();

        // scores s[i][j] for q = q0+ty*4+i, k = k0+tx*4+j
        float s[4][4];
        #pragma unroll
        for (int i = 0; i < 4; i++)
            #pragma unroll
            for (int j = 0; j < 4; j++) s[i][j] = 0.0f;
        #pragma unroll 8
        for (int d = 0; d < 64; d++) {
            float4 a4 = *(const float4*)&Qs[d][ty * 4];
            float4 b4 = *(const float4*)&KPs[d][tx * 4];
            float a[4] = {a4.x, a4.y, a4.z, a4.w};
            float bq[4] = {b4.x, b4.y, b4.z, b4.w};
            #pragma unroll
            for (int i = 0; i < 4; i++)
                #pragma unroll
                for (int j = 0; j < 4; j++) s[i][j] += a[i] * bq[j];
        }

        // scale + mask (faithful: -1e9 fill)
        if (mask_mode == 0) {
            int mv[4];
            #pragma unroll
            for (int j = 0; j < 4; j++) mv[j] = mask[(size_t)b * SK + k0 + tx * 4 + j];
            #pragma unroll
            for (int i = 0; i < 4; i++)
                #pragma unroll
                for (int j = 0; j < 4; j++) {
                    float v = s[i][j] * 0.125f;
                    s[i][j] = (mv[j] == 0) ? -1e9f : v;
                }
        } else {
            #pragma unroll
            for (int i = 0; i < 4; i++) {
                const int* mp = mask + ((size_t)b * SQ + q0 + ty * 4 + i) * SK + k0 + tx * 4;
                #pragma unroll
                for (int j = 0; j < 4; j++) {
                    float v = s[i][j] * 0.125f;
                    s[i][j] = (mp[j] == 0) ? -1e9f : v;
                }
            }
        }

        // online softmax update (row reduce across the 16 tx lanes)
        float p[4][4];
        #pragma unroll
        for (int i = 0; i < 4; i++) {
            float rm = fmaxf(fmaxf(s[i][0], s[i][1]), fmaxf(s[i][2], s[i][3]));
            rm = fmaxf(rm, __shfl_xor(rm, 1));
            rm = fmaxf(rm, __shfl_xor(rm, 2));
            rm = fmaxf(rm, __shfl_xor(rm, 4));
            rm = fmaxf(rm, __shfl_xor(rm, 8));
            float mn = fmaxf(m[i], rm);          // finite: s >= -1e9 always
            float sc = expf(m[i] - mn);          // expf(-inf)=0 on first tile
            float rs = 0.0f;
            #pragma unroll
            for (int j = 0; j < 4; j++) { p[i][j] = expf(s[i][j] - mn); rs += p[i][j]; }
            rs += __shfl_xor(rs, 1);
            rs += __shfl_xor(rs, 2);
            rs += __shfl_xor(rs, 4);
            rs += __shfl_xor(rs, 8);
            l[i] = l[i] * sc + rs;
            m[i] = mn;
            #pragma unroll
            for (int j = 0; j < 4; j++) o[i][j] *= sc;
        }

        __syncthreads();   // all lanes done reading KPs as K
        // write P transposed into K buffer: KPs[k][q] = P[q][k]
        #pragma unroll
        for (int j = 0; j < 4; j++)
            *(float4*)&KPs[tx * 4 + j][ty * 4] =
                make_float4(p[0][j], p[1][j], p[2][j], p[3][j]);
        __syncthreads();

        // o[i][j] += sum_k P[q][k] * V[k][d]
        #pragma unroll 8
        for (int kk = 0; kk < 64; kk++) {
            float4 a4 = *(const float4*)&KPs[kk][ty * 4];
            float4 b4 = *(const float4*)&Vs[kk][tx * 4];
            float a[4] = {a4.x, a4.y, a4.z, a4.w};
            float bv[4] = {b4.x, b4.y, b4.z, b4.w};
            #pragma unroll
            for (int i = 0; i < 4; i++)
                #pragma unroll
                for (int j = 0; j < 4; j++) o[i][j] += a[i] * bv[j];
        }
    }

    float* op = out + ((size_t)b * SQ + q0) * HD + h * HDIM;
    #pragma unroll
    for (int i = 0; i < 4; i++) {
        float inv = 1.0f / l[i];
        *(float4*)&op[(size_t)(ty * 4 + i) * HD + tx * 4] =
            make_float4(o[i][0] * inv, o[i][1] * inv, o[i][2] * inv, o[i][3] * inv);
    }
}

// ---------- in-place per-row log-softmax over fp32 logits ----------
__global__ __launch_bounds__(256) void logsoftmax_kernel(float* __restrict__ p, int N)
{
    int row = blockIdx.x, tid = threadIdx.x;
    float* r = p + (size_t)row * N;
    __shared__ float red[256];
    float m = -INFINITY;
    for (int i = tid; i < N; i += 256) m = fmaxf(m, r[i]);
    red[tid] = m; __syncthreads();
    for (int s = 128; s; s >>= 1) { if (tid < s) red[tid] = fmaxf(red[tid], red[tid + s]); __syncthreads(); }
    m = red[0]; __syncthreads();
    float ssum = 0.0f;
    for (int i = tid; i < N; i += 256) ssum += expf(r[i] - m);
    red[tid] = ssum; __syncthreads();
    for (int s = 128; s; s >>= 1) { if (tid < s) red[tid] += red[tid + s]; __syncthreads(); }
    float lse = m + logf(red[0]);
    __syncthreads();
    for (int i = tid; i < N; i += 256) r[i] = r[i] - lse;
}

// ---------- orchestration ----------
extern "C" void kernel_launch(void* const* d_in, const int* in_sizes, int n_in,
                              void* d_out, int out_size, void* d_ws, size_t ws_size,
                              hipStream_t stream)
{
    (void)in_sizes; (void)n_in; (void)out_size;
    const int* src     = (const int*)d_in[0];
    const int* tgt     = (const int*)d_in[1];
    const int* msk_src = (const int*)d_in[2];
    const int* msk_tgt = (const int*)d_in[3];
    const float* src_emb = (const float*)d_in[4];
    const float* tgt_emb = (const float*)d_in[5];
    const float* ew[16]; for (int i = 0; i < 16; i++) ew[i] = (const float*)d_in[6 + i];
    const float* dw[16]; for (int i = 0; i < 16; i++) dw[i] = (const float*)d_in[22 + i];
    const float* dln3_g = (const float*)d_in[38];
    const float* dln3_b = (const float*)d_in[39];
    const float* encn_g = (const float*)d_in[40];
    const float* encn_b = (const float*)d_in[41];
    const float* decn_g = (const float*)d_in[42];
    const float* decn_b = (const float*)d_in[43];
    const float* gen_w  = (const float*)d_in[44];
    const float* gen_b  = (const float*)d_in[45];

    const size_t SLOT = (size_t)4096 * 512;   // 2M floats = 8 MB
    float* ws = (float*)d_ws;
    // xn ALWAYS lives in d_ws (generator GEMM reads it while writing d_out).
    float* xn = ws;
    // The six big slots live in d_ws if it's large enough, else in the (dead
    // until generator) 262 MB d_out region. ws_size is constant across calls,
    // so the branch is graph-capture safe.
    bool ws_ok = ws_size >= 7 * SLOT * sizeof(float);
    float* big = ws_ok ? (ws + SLOT) : (float*)d_out;
    float* x   = big;                // activations (enc x, later dec y)
    float* z   = big + SLOT;         // encoder memory (persists)
    float* sq  = big + 2 * SLOT;     // Q
    float* skb = big + 3 * SLOT;     // K
    float* sv  = big + 4 * SLOT;     // V
    float* sa  = big + 5 * SLOT;     // attention output
    float* ff  = sq;                 // FF mid aliases q/k/v/attn (8M floats)

    auto gemm = [&](const float* A, const float* B, const float* bias,
                    const float* res, float* C, int M, int N, int K, int relu) {
        gemm_kernel<<<dim3(N / 64, M / 64), 256, 0, stream>>>(
            A, B, bias, res, C, M, N, K, relu);
    };

    const int Me = BSZ * LSRC;   // 4096
    const int Md = BSZ * LTGT;   // 2048
    const int WSQ = DMODEL * DMODEL;  // per-layer attn weight stride

    // ===== encoder =====
    embed_pe_kernel<<<(Me * DMODEL) / 256, 256, 0, stream>>>(src, src_emb, x, LSRC);
    for (int i = 0; i < NLAYERS; i++) {
        layernorm_kernel<<<Me, 256, 0, stream>>>(x, ew[12] + i * 512, ew[13] + i * 512, xn);
        gemm(xn, ew[0] + i * WSQ, ew[1] + i * 512, nullptr, sq,  Me, 512, 512, 0);
        gemm(xn, ew[2] + i * WSQ, ew[3] + i * 512, nullptr, skb, Me, 512, 512, 0);
        gemm(xn, ew[4] + i * WSQ, ew[5] + i * 512, nullptr, sv,  Me, 512, 512, 0);
        attn_kernel<<<dim3(LSRC / 64, NHEADS, BSZ), 256, 0, stream>>>(
            sq, skb, sv, msk_src, 0, sa, LSRC, LSRC);
        gemm(sa, ew[6] + i * WSQ, ew[7] + i * 512, x, x, Me, 512, 512, 0);
        layernorm_kernel<<<Me, 256, 0, stream>>>(x, ew[14] + i * 512, ew[15] + i * 512, xn);
        gemm(xn, ew[8]  + i * (512 * 2048), ew[9]  + i * 2048, nullptr, ff, Me, 2048, 512, 1);
        gemm(ff, ew[10] + i * (2048 * 512), ew[11] + i * 512,  x,       x,  Me, 512, 2048, 0);
    }
    layernorm_kernel<<<Me, 256, 0, stream>>>(x, encn_g, encn_b, z);

    // ===== decoder =====
    embed_pe_kernel<<<(Md * DMODEL) / 256, 256, 0, stream>>>(tgt, tgt_emb, x, LTGT);
    for (int i = 0; i < NLAYERS; i++) {
        // self-attention (causal mask)
        layernorm_kernel<<<Md, 256, 0, stream>>>(x, dw[12] + i * 512, dw[13] + i * 512, xn);
        gemm(xn, dw[0] + i * WSQ, dw[1] + i * 512, nullptr, sq,  Md, 512, 512, 0);
        gemm(xn, dw[2] + i * WSQ, dw[3] + i * 512, nullptr, skb, Md, 512, 512, 0);
        gemm(xn, dw[4] + i * WSQ, dw[5] + i * 512, nullptr, sv,  Md, 512, 512, 0);
        attn_kernel<<<dim3(LTGT / 64, NHEADS, BSZ), 256, 0, stream>>>(
            sq, skb, sv, msk_tgt, 1, sa, LTGT, LTGT);
        gemm(sa, dw[6] + i * WSQ, dw[7] + i * 512, x, x, Md, 512, 512, 0);
        // cross-attention (shares the same per-layer attention weights)
        layernorm_kernel<<<Md, 256, 0, stream>>>(x, dw[14] + i * 512, dw[15] + i * 512, xn);
        gemm(xn, dw[0] + i * WSQ, dw[1] + i * 512, nullptr, sq,  Md, 512, 512, 0);
        gemm(z,  dw[2] + i * WSQ, dw[3] + i * 512, nullptr, skb, Me, 512, 512, 0);
        gemm(z,  dw[4] + i * WSQ, dw[5] + i * 512, nullptr, sv,  Me, 512, 512, 0);
        attn_kernel<<<dim3(LTGT / 64, NHEADS, BSZ), 256, 0, stream>>>(
            sq, skb, sv, msk_src, 0, sa, LTGT, LSRC);
        gemm(sa, dw[6] + i * WSQ, dw[7] + i * 512, x, x, Md, 512, 512, 0);
        // feed-forward
        layernorm_kernel<<<Md, 256, 0, stream>>>(x, dln3_g + i * 512, dln3_b + i * 512, xn);
        gemm(xn, dw[8]  + i * (512 * 2048), dw[9]  + i * 2048, nullptr, ff, Md, 2048, 512, 1);
        gemm(ff, dw[10] + i * (2048 * 512), dw[11] + i * 512,  x,       x,  Md, 512, 2048, 0);
    }
    layernorm_kernel<<<Md, 256, 0, stream>>>(x, decn_g, decn_b, xn);

    // ===== generator + log-softmax (fp32 logits in d_out, then in-place) =====
    gemm_kernel<<<dim3(VOCAB / 64, Md / 64), 256, 0, stream>>>(
        xn, gen_w, gen_b, nullptr, (float*)d_out, Md, VOCAB, 512, 0);
    logsoftmax_kernel<<<Md, 256, 0, stream>>>((float*)d_out, VOCAB);
}